// Round 11
// baseline (5634.738 us; speedup 1.0000x reference)
//
#include <hip/hip_runtime.h>
#include <hip/hip_bf16.h>

#define SLEN 128
#define BAT 64
#define EDIM 512
#define HDIM 1024
#define VOC 10000
#define VPAD 10112     // 79 * 128
#define NWG_REC 192
#define TPB_REC 512

typedef short v8s __attribute__((ext_vector_type(8)));
typedef float v4f __attribute__((ext_vector_type(4)));
typedef unsigned short u16;

__device__ __forceinline__ u16 f2bf(float f) {
  unsigned u = __float_as_uint(f);
  u += 0x7fffu + ((u >> 16) & 1u);   // RNE
  return (u16)(u >> 16);
}
__device__ __forceinline__ float bf2f(u16 b) {
  return __uint_as_float(((unsigned)b) << 16);
}
__device__ __forceinline__ float sigm(float x) { return 1.f / (1.f + __expf(-x)); }
__device__ __forceinline__ float tanh_f(float x) { return 1.f - 2.f / (1.f + __expf(2.f * x)); }

// ---- LLC-point scalar state accessors (relaxed agent atomics, no fences) ---------
__device__ __forceinline__ void st_f32(float* p, float v) {
  __hip_atomic_store(p, v, __ATOMIC_RELAXED, __HIP_MEMORY_SCOPE_AGENT);
}
__device__ __forceinline__ float ld_f32(const float* p) {
  return __hip_atomic_load(p, __ATOMIC_RELAXED, __HIP_MEMORY_SCOPE_AGENT);
}
__device__ __forceinline__ float ld_bf16(const unsigned* base, int elem) {
  unsigned pr = __hip_atomic_load(base + (elem >> 1), __ATOMIC_RELAXED, __HIP_MEMORY_SCOPE_AGENT);
  return bf2f((u16)((elem & 1) ? (pr >> 16) : (pr & 0xffffu)));
}
// bf16 pair store: lanes l (even) and l^1 hold adjacent elements; even lane stores u32
__device__ __forceinline__ void st_bf16_pair(unsigned* base, int elem, u16 val, int l) {
  unsigned p = (unsigned)__shfl_xor((int)val, 1);
  if ((l & 1) == 0)
    __hip_atomic_store(base + (elem >> 1), (unsigned)val | (p << 16),
                       __ATOMIC_RELAXED, __HIP_MEMORY_SCOPE_AGENT);
}

// ---------------- fence-free direct-poll grid barrier + L2 acquire-inv ------------
// Poll sc flags, then an agent acquire fence (buffer_inv, no writeback): local L2
// drops any stale state lines so the phase's NORMAL (L2-cached) A-loads fill
// fresh from LLC. All k_recur stores are sc (LLC-point) -> no dirty lines to lose.
__device__ __forceinline__ void gbar(int* bar, int ph, int wg, int t) {
  asm volatile("s_waitcnt vmcnt(0) lgkmcnt(0)" ::: "memory");
  __syncthreads();
  if (t == 0)
    __hip_atomic_store(&bar[wg], ph, __ATOMIC_RELAXED, __HIP_MEMORY_SCOPE_AGENT);
  if (t < 64) {
    for (;;) {
      int v0 = __hip_atomic_load(&bar[t],       __ATOMIC_RELAXED, __HIP_MEMORY_SCOPE_AGENT);
      int v1 = __hip_atomic_load(&bar[64 + t],  __ATOMIC_RELAXED, __HIP_MEMORY_SCOPE_AGENT);
      int v2 = __hip_atomic_load(&bar[128 + t], __ATOMIC_RELAXED, __HIP_MEMORY_SCOPE_AGENT);
      if (__all((v0 >= ph) & (v1 >= ph) & (v2 >= ph))) break;
      __builtin_amdgcn_s_sleep(1);
    }
  }
  __syncthreads();
  __builtin_amdgcn_fence(__ATOMIC_ACQUIRE, "agent");   // buffer_inv: L2 refresh
}

// ---- cooperative LDS-staged 64x(32cols)x1024 GEMM (depth-3 ring, L2-cached A) ----
// All 8 waves pull A (64x1024 bf16, row stride 2KB) through a 2x8KB LDS double
// buffer (16 chunks of 64 k-elems; 1 dwordx4/thread/chunk; 3 chunks in flight).
// A-loads are NORMAL loads: first WG per XCD fills L2 from LLC, rest hit L2.
__device__ __forceinline__ v4f gemm_staged(const char* Asrc, char* stage,
                                           const char* bb, int swz,
                                           int t, int rg, int lr, int lk2) {
  const char* gp = Asrc + (t >> 3) * 2048 + (t & 7) * 16;
  char* wp = stage + (t >> 3) * 128 + (((t & 7) * 16) ^ (((t >> 3) & 7) << 4));
  const char* rp = stage + (rg * 16 + lr) * 128;
  v4f acc{0.f, 0.f, 0.f, 0.f};
  v8s sreg[3];
  asm volatile("global_load_dwordx4 %0, %1, off" : "=v"(sreg[0]) : "v"(gp));
  asm volatile("global_load_dwordx4 %0, %1, off offset:128" : "=v"(sreg[1]) : "v"(gp));
  asm volatile("global_load_dwordx4 %0, %1, off offset:256" : "=v"(sreg[2]) : "v"(gp));
  asm volatile("s_waitcnt vmcnt(2)" ::: "memory");
  __builtin_amdgcn_sched_barrier(0);
  *(v8s*)wp = sreg[0];
  __syncthreads();
#pragma unroll
  for (int c = 0; c < 16; ++c) {
    if (c < 13)
      asm volatile("global_load_dwordx4 %0, %1, off offset:%2"
                   : "=v"(sreg[c % 3]) : "v"(gp), "i"((c + 3) * 128));
    if (c < 15) {
      if (c < 13)       asm volatile("s_waitcnt vmcnt(2)" ::: "memory");
      else if (c == 13) asm volatile("s_waitcnt vmcnt(1)" ::: "memory");
      else              asm volatile("s_waitcnt vmcnt(0)" ::: "memory");
      __builtin_amdgcn_sched_barrier(0);
      *(v8s*)(wp + ((c + 1) & 1) * 8192) = sreg[(c + 1) % 3];
    }
    const char* buf = rp + (c & 1) * 8192;
#pragma unroll
    for (int ls = 0; ls < 2; ++ls) {
      v8s a = *(const v8s*)(buf + ((ls * 64 + lk2) ^ swz));
      v8s b = *(const v8s*)(bb + (((c * 2 + ls) * 64 + lk2) ^ swz));
      acc = __builtin_amdgcn_mfma_f32_16x16x32_bf16(a, b, acc, 0, 0, 0);
    }
    __syncthreads();
  }
  return acc;
}

// ---------------- persistent 2-layer GRU recurrence -------------------------------
// 192 WGs x 512 thr. LDS: [0,64K) P1 weights (32 cols); [64K,128K) P2 weights
// (32 cols, wg<96); [128K,144K) A-stage dbuf. State via sc LLC atomics; A-operand
// via L2-cached loads + per-phase acquire-inv (in gbar).
// Per tick (2 barriers):
//  P1: rz0(T) wg0-63 | xp1(T-1) wg64-159 | ht1(T-2) wg160-191   (32 cols, staged A)
//  P2: ht0(T) wg0-31 | rz1(T-1) wg32-95                          (32 cols, staged A)
__global__ void __launch_bounds__(TPB_REC, 2) k_recur(
    const u16* __restrict__ Uh0b, const u16* __restrict__ Wx1b, const u16* __restrict__ Uh1b,
    const float* __restrict__ b0, const float* __restrict__ b1,
    const u16* __restrict__ xa0,
    float* __restrict__ h0f, u16* __restrict__ h0b,
    float* __restrict__ h1f, u16* __restrict__ h1b,
    u16* __restrict__ a2, float* __restrict__ z0,
    u16* __restrict__ a5, float* __restrict__ z1,
    u16* __restrict__ xp1,
    u16* __restrict__ hs1,
    float* __restrict__ outh,
    int* __restrict__ bar) {
  extern __shared__ char smem[];
  const int wg = blockIdx.x;
  const int t = threadIdx.x;
  const int w = t >> 6;
  const int l = t & 63;
  const int lr = l & 15;
  const int lk2 = (l >> 4) * 16;
  const int rg = w >> 1, cg = w & 1;
  const int rbase = rg * 16 + ((l >> 4) << 2);
  const int swz = (lr & 7) << 4;
  char* stage = smem + 131072;

  unsigned* a2u  = (unsigned*)a2;
  unsigned* a5u  = (unsigned*)a5;
  unsigned* h0bu = (unsigned*)h0b;
  unsigned* h1bu = (unsigned*)h1b;
  unsigned* xpu  = (unsigned*)xp1;
  unsigned* hs1u = (unsigned*)hs1;

  // ---- one-time weight staging into swizzled LDS ----
  {
    const u16* w1src; int w1row0;
    if (wg < 64)       { w1src = Uh0b; w1row0 = wg * 32; }
    else if (wg < 160) { w1src = Wx1b; w1row0 = (wg - 64) * 32; }
    else               { w1src = Uh1b; w1row0 = 2048 + (wg - 160) * 32; }
    for (int i = t; i < 4096; i += TPB_REC) {          // 32 cols * 128 x 16B
      int c = i >> 7, j = i & 127;
      v8s v = *(const v8s*)(w1src + (size_t)(w1row0 + c) * HDIM + j * 8);
      *(v8s*)(smem + c * 2048 + ((j * 16) ^ ((c & 7) << 4))) = v;
    }
    if (wg < 96) {
      const u16* w2src; int w2row0;
      if (wg < 32) { w2src = Uh0b; w2row0 = 2048 + wg * 32; }
      else         { w2src = Uh1b; w2row0 = (wg - 32) * 32; }
      for (int i = t; i < 4096; i += TPB_REC) {
        int c = i >> 7, j = i & 127;
        v8s v = *(const v8s*)(w2src + (size_t)(w2row0 + c) * HDIM + j * 8);
        *(v8s*)(smem + 65536 + c * 2048 + ((j * 16) ^ ((c & 7) << 4))) = v;
      }
    }
    __syncthreads();
  }

  const char* bb1 = smem + (cg * 16 + lr) * 2048;
  const char* bb2 = smem + 65536 + (cg * 16 + lr) * 2048;

  for (int T = 0; T <= SLEN + 1; ++T) {
    // ---------------- Phase 1 ----------------
    if (wg < 64) {
      if (T < SLEN) {          // rz0(T): A=h0b, B=Uh0[rz]
        const int cglob = wg * 32 + cg * 16 + lr;      // 0..2047
        const int g = cglob >> 10;                     // uniform per WG
        const int o = cglob & 1023;
        const float bias = b0[g * HDIM + o];
        float xv[4], hv[4];
#pragma unroll
        for (int r = 0; r < 4; ++r) {
          int b = rbase + r;
          xv[r] = bf2f(xa0[((T * 3 + g) * BAT + b) * HDIM + o]);
          if (g == 0) hv[r] = ld_f32(&h0f[b * HDIM + o]);
        }
        v4f acc = gemm_staged((const char*)h0b, stage, bb1, swz, t, rg, lr, lk2);
#pragma unroll
        for (int r = 0; r < 4; ++r) {
          int b = rbase + r;
          float s = sigm(acc[r] + xv[r] + bias);
          if (g == 0) st_bf16_pair(a2u, b * HDIM + o, f2bf(s * hv[r]), l);
          else        st_f32(&z0[b * HDIM + o], s);
        }
      }
    } else if (wg < 160) {
      if (T >= 1 && T <= SLEN) {   // xp1(T-1): A=h0b, B=Wx1
        const int n = (wg - 64) * 32 + cg * 16 + lr;   // 0..3071
        v4f acc = gemm_staged((const char*)h0b, stage, bb1, swz, t, rg, lr, lk2);
        unsigned* xp = xpu + ((((T - 1) & 1) * (BAT * 3 * HDIM)) >> 1);
#pragma unroll
        for (int r = 0; r < 4; ++r)
          st_bf16_pair(xp, (rbase + r) * 3072 + n, f2bf(acc[r]), l);
      }
    } else {
      if (T >= 2) {                // ht1(T-2): A=a5, B=Uh1[h]
        const int t5 = T - 2;
        const int o = (wg - 160) * 32 + cg * 16 + lr;  // 0..1023
        const unsigned* xp = xpu + (((t5 & 1) * (BAT * 3 * HDIM)) >> 1);
        const float bias = b1[2 * HDIM + o];
        float pv[4], zv[4], hv[4];
#pragma unroll
        for (int r = 0; r < 4; ++r) {
          int b = rbase + r;
          pv[r] = ld_bf16(xp, b * 3072 + 2048 + o);
          zv[r] = ld_f32(&z1[b * HDIM + o]);
          hv[r] = ld_f32(&h1f[b * HDIM + o]);
        }
        v4f acc = gemm_staged((const char*)a5, stage, bb1, swz, t, rg, lr, lk2);
#pragma unroll
        for (int r = 0; r < 4; ++r) {
          int b = rbase + r;
          float ht = tanh_f(pv[r] + acc[r] + bias);
          float hn = (1.f - zv[r]) * hv[r] + zv[r] * ht;
          u16 hb = f2bf(hn);
          st_f32(&h1f[b * HDIM + o], hn);
          st_bf16_pair(h1bu, b * HDIM + o, hb, l);
          st_bf16_pair(hs1u, (int)(((size_t)t5 * BAT + b) * HDIM + o), hb, l);
          if (t5 == SLEN - 1) st_f32(&outh[(size_t)BAT * HDIM + b * HDIM + o], hn);
        }
      }
    }
    gbar(bar, 2 * T + 1, wg, t);
    // ---------------- Phase 2 ----------------
    if (wg < 32) {
      if (T < SLEN) {              // ht0(T): A=a2, B=Uh0[h]
        const int o = wg * 32 + cg * 16 + lr;          // 0..1023
        const float bias = b0[2 * HDIM + o];
        float xv[4], zv[4], hv[4];
#pragma unroll
        for (int r = 0; r < 4; ++r) {
          int b = rbase + r;
          xv[r] = bf2f(xa0[((T * 3 + 2) * BAT + b) * HDIM + o]);
          zv[r] = ld_f32(&z0[b * HDIM + o]);
          hv[r] = ld_f32(&h0f[b * HDIM + o]);
        }
        v4f acc = gemm_staged((const char*)a2, stage, bb2, swz, t, rg, lr, lk2);
#pragma unroll
        for (int r = 0; r < 4; ++r) {
          int b = rbase + r;
          float ht = tanh_f(xv[r] + acc[r] + bias);
          float hn = (1.f - zv[r]) * hv[r] + zv[r] * ht;
          st_f32(&h0f[b * HDIM + o], hn);
          st_bf16_pair(h0bu, b * HDIM + o, f2bf(hn), l);
          if (T == SLEN - 1) st_f32(&outh[b * HDIM + o], hn);
        }
      }
    } else if (wg < 96) {
      if (T >= 1 && T <= SLEN) {   // rz1(T-1): A=h1b, B=Uh1[rz]
        const int t4 = T - 1;
        const int cglob = (wg - 32) * 32 + cg * 16 + lr;  // 0..2047
        const int g = cglob >> 10;                        // uniform per WG
        const int o = cglob & 1023;
        const unsigned* xp = xpu + (((t4 & 1) * (BAT * 3 * HDIM)) >> 1);
        const float bias = b1[g * HDIM + o];
        float pv[4], hv[4];
#pragma unroll
        for (int r = 0; r < 4; ++r) {
          int b = rbase + r;
          pv[r] = ld_bf16(xp, b * 3072 + g * HDIM + o);
          if (g == 0) hv[r] = ld_f32(&h1f[b * HDIM + o]);
        }
        v4f acc = gemm_staged((const char*)h1b, stage, bb2, swz, t, rg, lr, lk2);
#pragma unroll
        for (int r = 0; r < 4; ++r) {
          int b = rbase + r;
          float s = sigm(acc[r] + pv[r] + bias);
          if (g == 0) st_bf16_pair(a5u, b * HDIM + o, f2bf(s * hv[r]), l);
          else        st_f32(&z1[b * HDIM + o], s);
        }
      }
    }
    gbar(bar, 2 * T + 2, wg, t);
  }
}

// ---------------- m97-style 128x128 bf16 GEMM ------------------------------------
// MODE 0: xa0 = gather(emb)[8192,512] x Wx0[3072,512]^T -> bf16 out in (S,3,B,H) layout
// MODE 1: logits = hs1[8192,1024] x Wd[VPAD,1024]^T + bd -> f32 (8192,10000)
template <int MODE>
__global__ void __launch_bounds__(256) k_gemm(
    const u16* __restrict__ A, const u16* __restrict__ Bw,
    const int* __restrict__ gidx, const float* __restrict__ bias,
    void* __restrict__ Out) {
  constexpr int K = MODE ? 1024 : 512;
  constexpr int NB_N = MODE ? (VPAD / 128) : (3072 / 128);

  __shared__ u16 sA[128 * 64];
  __shared__ u16 sB[128 * 64];

  const int nwg = gridDim.x;
  const int cpx = nwg >> 3;
  const int bid = blockIdx.x;
  const int swz = (bid & 7) * cpx + (bid >> 3);
  const int bm = swz / NB_N, bn = swz % NB_N;
  const int m0 = bm * 128, n0 = bn * 128;

  const int t = threadIdx.x;
  const int w = t >> 6, l = t & 63;
  const int lr = l & 15, lk = (l >> 4) * 8;
  const int wm = (w >> 1) * 64, wn = (w & 1) * 64;
  const int kc = (t & 7) * 8;

  int arowg[4];
#pragma unroll
  for (int i = 0; i < 4; ++i) {
    int row = m0 + i * 32 + (t >> 3);
    arowg[i] = (MODE == 0) ? gidx[row] : row;
  }
  int brow[4];
#pragma unroll
  for (int i = 0; i < 4; ++i) brow[i] = n0 + i * 32 + (t >> 3);

  v4f acc[4][4];
#pragma unroll
  for (int mi = 0; mi < 4; ++mi)
#pragma unroll
    for (int ni = 0; ni < 4; ++ni) acc[mi][ni] = v4f{0.f, 0.f, 0.f, 0.f};

  for (int k0 = 0; k0 < K; k0 += 64) {
    __syncthreads();
#pragma unroll
    for (int i = 0; i < 4; ++i) {
      const u16* src = A + (size_t)arowg[i] * K + k0 + kc;
      __builtin_amdgcn_global_load_lds((const __attribute__((address_space(1))) void*)src,
                                       (__attribute__((address_space(3))) void*)(sA + i * 2048 + w * 512),
                                       16, 0, 0);
    }
#pragma unroll
    for (int i = 0; i < 4; ++i) {
      const u16* src = Bw + (size_t)brow[i] * K + k0 + kc;
      __builtin_amdgcn_global_load_lds((const __attribute__((address_space(1))) void*)src,
                                       (__attribute__((address_space(3))) void*)(sB + i * 2048 + w * 512),
                                       16, 0, 0);
    }
    asm volatile("s_waitcnt vmcnt(0)" ::: "memory");
    __syncthreads();
#pragma unroll
    for (int ks = 0; ks < 2; ++ks) {
      v8s af[4], bfr[4];
#pragma unroll
      for (int mi = 0; mi < 4; ++mi) af[mi] = *(const v8s*)&sA[(wm + mi * 16 + lr) * 64 + ks * 32 + lk];
#pragma unroll
      for (int ni = 0; ni < 4; ++ni) bfr[ni] = *(const v8s*)&sB[(wn + ni * 16 + lr) * 64 + ks * 32 + lk];
#pragma unroll
      for (int mi = 0; mi < 4; ++mi)
#pragma unroll
        for (int ni = 0; ni < 4; ++ni)
          acc[mi][ni] = __builtin_amdgcn_mfma_f32_16x16x32_bf16(af[mi], bfr[ni], acc[mi][ni], 0, 0, 0);
    }
  }

#pragma unroll
  for (int mi = 0; mi < 4; ++mi)
#pragma unroll
    for (int ni = 0; ni < 4; ++ni)
#pragma unroll
      for (int r = 0; r < 4; ++r) {
        int grow = m0 + wm + mi * 16 + ((l >> 4) << 2) + r;
        int gcol = n0 + wn + ni * 16 + lr;
        float v = acc[mi][ni][r];
        if (MODE == 0) {
          int s = grow >> 6, b = grow & 63;
          int g = gcol >> 10, o = gcol & 1023;
          ((u16*)Out)[(((size_t)s * 3 + g) * BAT + b) * HDIM + o] = f2bf(v);
        } else {
          if (gcol < VOC) ((float*)Out)[(size_t)grow * VOC + gcol] = v + bias[gcol];
        }
      }
}

// ---------------- small helper kernels --------------------------------------------
__global__ void k_cvt(const float* __restrict__ src, u16* __restrict__ dst, int n, int nsrc) {
  int i = (blockIdx.x * 256 + threadIdx.x) * 4;
  if (i >= n) return;
#pragma unroll
  for (int j = 0; j < 4; ++j) {
    int idx = i + j;
    if (idx < n) dst[idx] = (idx < nsrc) ? f2bf(src[idx]) : (u16)0;
  }
}

__global__ void k_init(const float* __restrict__ hidden,
                       float* h0f, u16* h0b, float* h1f, u16* h1b, int* bar) {
  int i = blockIdx.x * 256 + threadIdx.x;
  if (i < BAT * HDIM) {
    float v0 = hidden[i];
    float v1 = hidden[BAT * HDIM + i];
    h0f[i] = v0; h0b[i] = f2bf(v0);
    h1f[i] = v1; h1b[i] = f2bf(v1);
  }
  if (i < 512) bar[i] = 0;
}

// ---------------- launcher ---------------------------------------------------------
extern "C" void kernel_launch(void* const* d_in, const int* in_sizes, int n_in,
                              void* d_out, int out_size, void* d_ws, size_t ws_size,
                              hipStream_t stream) {
  const int*   inp = (const int*)d_in[0];
  const float* hid = (const float*)d_in[1];
  const float* emb = (const float*)d_in[2];
  const float* Wx0 = (const float*)d_in[3];
  const float* Uh0 = (const float*)d_in[4];
  const float* b0  = (const float*)d_in[5];
  const float* Wx1 = (const float*)d_in[6];
  const float* Uh1 = (const float*)d_in[7];
  const float* b1  = (const float*)d_in[8];
  const float* Wd  = (const float*)d_in[9];
  const float* bd  = (const float*)d_in[10];

  char* ws = (char*)d_ws;
  size_t off = 0;
  auto alloc = [&](size_t bytes) {
    void* p = ws + off;
    off = (off + bytes + 255) & ~(size_t)255;
    return p;
  };
  u16* emb_b = (u16*)alloc(sizeof(u16) * (size_t)VOC * EDIM);
  u16* Wx0_b = (u16*)alloc(sizeof(u16) * 3 * HDIM * EDIM);
  u16* Uh0_b = (u16*)alloc(sizeof(u16) * 3 * HDIM * HDIM);
  u16* Wx1_b = (u16*)alloc(sizeof(u16) * 3 * HDIM * HDIM);
  u16* Uh1_b = (u16*)alloc(sizeof(u16) * 3 * HDIM * HDIM);
  u16* Wd_b  = (u16*)alloc(sizeof(u16) * (size_t)VPAD * HDIM);
  u16* xa0_b = (u16*)alloc(sizeof(u16) * (size_t)SLEN * 3 * BAT * HDIM);
  u16* hs1_b = (u16*)alloc(sizeof(u16) * (size_t)SLEN * BAT * HDIM);
  u16* xp1   = (u16*)alloc(sizeof(u16) * 2 * BAT * 3 * HDIM);
  float* h0f = (float*)alloc(sizeof(float) * BAT * HDIM);
  float* h1f = (float*)alloc(sizeof(float) * BAT * HDIM);
  u16* h0b   = (u16*)alloc(sizeof(u16) * BAT * HDIM);
  u16* h1b   = (u16*)alloc(sizeof(u16) * BAT * HDIM);
  u16* a2    = (u16*)alloc(sizeof(u16) * BAT * HDIM);
  u16* a5    = (u16*)alloc(sizeof(u16) * BAT * HDIM);
  float* z0  = (float*)alloc(sizeof(float) * BAT * HDIM);
  float* z1  = (float*)alloc(sizeof(float) * BAT * HDIM);
  int* bar   = (int*)alloc(sizeof(int) * 512);

  float* logits = (float*)d_out;
  float* outh = logits + (size_t)SLEN * BAT * VOC;

  auto cvt = [&](const float* s, u16* d, int n, int nsrc) {
    k_cvt<<<dim3((n / 4 + 255) / 256), dim3(256), 0, stream>>>(s, d, n, nsrc);
  };
  cvt(emb, emb_b, VOC * EDIM, VOC * EDIM);
  cvt(Wx0, Wx0_b, 3 * HDIM * EDIM, 3 * HDIM * EDIM);
  cvt(Uh0, Uh0_b, 3 * HDIM * HDIM, 3 * HDIM * HDIM);
  cvt(Wx1, Wx1_b, 3 * HDIM * HDIM, 3 * HDIM * HDIM);
  cvt(Uh1, Uh1_b, 3 * HDIM * HDIM, 3 * HDIM * HDIM);
  cvt(Wd, Wd_b, VPAD * HDIM, VOC * HDIM);
  k_init<<<dim3(256), dim3(256), 0, stream>>>(hid, h0f, h0b, h1f, h1b, bar);

  k_gemm<0><<<dim3(64 * 24), dim3(256), 0, stream>>>(emb_b, Wx0_b, inp, (const float*)nullptr, (void*)xa0_b);

  (void)hipFuncSetAttribute(reinterpret_cast<const void*>(k_recur),
                            hipFuncAttributeMaxDynamicSharedMemorySize, 147456);
  k_recur<<<dim3(NWG_REC), dim3(TPB_REC), 147456, stream>>>(
      Uh0_b, Wx1_b, Uh1_b, b0, b1, xa0_b,
      h0f, h0b, h1f, h1b, a2, z0, a5, z1, xp1, hs1_b, outh, bar);

  k_gemm<1><<<dim3(64 * 79), dim3(256), 0, stream>>>(hs1_b, Wd_b, (const int*)nullptr, bd, d_out);
}

// Round 12
// 2903.970 us; speedup vs baseline: 1.9404x; 1.9404x over previous
//
#include <hip/hip_runtime.h>
#include <hip/hip_bf16.h>

#define SLEN 128
#define BAT 64
#define EDIM 512
#define HDIM 1024
#define VOC 10000
#define VPAD 10112     // 79 * 128
#define NWG_REC 192
#define TPB_REC 512

typedef short v8s __attribute__((ext_vector_type(8)));
typedef float v4f __attribute__((ext_vector_type(4)));
typedef unsigned short u16;

__device__ __forceinline__ u16 f2bf(float f) {
  unsigned u = __float_as_uint(f);
  u += 0x7fffu + ((u >> 16) & 1u);   // RNE
  return (u16)(u >> 16);
}
__device__ __forceinline__ float bf2f(u16 b) {
  return __uint_as_float(((unsigned)b) << 16);
}
__device__ __forceinline__ float sigm(float x) { return 1.f / (1.f + __expf(-x)); }
__device__ __forceinline__ float tanh_f(float x) { return 1.f - 2.f / (1.f + __expf(2.f * x)); }

// ---- LLC-point scalar state accessors (relaxed agent atomics, no fences) ---------
__device__ __forceinline__ void st_f32(float* p, float v) {
  __hip_atomic_store(p, v, __ATOMIC_RELAXED, __HIP_MEMORY_SCOPE_AGENT);
}
__device__ __forceinline__ float ld_f32(const float* p) {
  return __hip_atomic_load(p, __ATOMIC_RELAXED, __HIP_MEMORY_SCOPE_AGENT);
}
__device__ __forceinline__ float ld_bf16(const unsigned* base, int elem) {
  unsigned pr = __hip_atomic_load(base + (elem >> 1), __ATOMIC_RELAXED, __HIP_MEMORY_SCOPE_AGENT);
  return bf2f((u16)((elem & 1) ? (pr >> 16) : (pr & 0xffffu)));
}
// bf16 pair store: lanes l (even) and l^1 hold adjacent elements; even lane stores u32
__device__ __forceinline__ void st_bf16_pair(unsigned* base, int elem, u16 val, int l) {
  unsigned p = (unsigned)__shfl_xor((int)val, 1);
  if ((l & 1) == 0)
    __hip_atomic_store(base + (elem >> 1), (unsigned)val | (p << 16),
                       __ATOMIC_RELAXED, __HIP_MEMORY_SCOPE_AGENT);
}

// ---------------- fence-free direct-poll grid barrier -----------------------------
__device__ __forceinline__ void gbar(int* bar, int ph, int wg, int t) {
  asm volatile("s_waitcnt vmcnt(0) lgkmcnt(0)" ::: "memory");
  __syncthreads();
  if (t == 0)
    __hip_atomic_store(&bar[wg], ph, __ATOMIC_RELAXED, __HIP_MEMORY_SCOPE_AGENT);
  if (t < 64) {
    for (;;) {
      int v0 = __hip_atomic_load(&bar[t],       __ATOMIC_RELAXED, __HIP_MEMORY_SCOPE_AGENT);
      int v1 = __hip_atomic_load(&bar[64 + t],  __ATOMIC_RELAXED, __HIP_MEMORY_SCOPE_AGENT);
      int v2 = __hip_atomic_load(&bar[128 + t], __ATOMIC_RELAXED, __HIP_MEMORY_SCOPE_AGENT);
      if (__all((v0 >= ph) & (v1 >= ph) & (v2 >= ph))) break;
      __builtin_amdgcn_s_sleep(1);
    }
  }
  __syncthreads();
}

// ---- cooperative LDS-staged 64x(32cols)x1024 GEMM, depth-5 prefetch ring ---------
// All 8 waves pull A (64x1024 bf16, row stride 2KB) through a 2x8KB LDS double
// buffer (16 chunks of 64 k-elems; 1 dwordx4/thread/chunk; 5 chunks in flight).
// Same write/read buffer ordering as the proven depth-3 version; only ring depth
// differs (covers ~5/3 more LLC latency, burst 5/8 of the regressed depth-8).
__device__ __forceinline__ v4f gemm_staged(const char* Asrc, char* stage,
                                           const char* bb, int swz,
                                           int t, int rg, int lr, int lk2) {
  const char* gp = Asrc + (t >> 3) * 2048 + (t & 7) * 16;
  char* wp = stage + (t >> 3) * 128 + (((t & 7) * 16) ^ (((t >> 3) & 7) << 4));
  const char* rp = stage + (rg * 16 + lr) * 128;
  v4f acc{0.f, 0.f, 0.f, 0.f};
  v8s sreg[5];
#pragma unroll
  for (int j = 0; j < 5; ++j)
    asm volatile("global_load_dwordx4 %0, %1, off offset:%2 sc0 sc1"
                 : "=v"(sreg[j]) : "v"(gp), "i"(j * 128));
  asm volatile("s_waitcnt vmcnt(4)" ::: "memory");
  __builtin_amdgcn_sched_barrier(0);
  *(v8s*)wp = sreg[0];
  __syncthreads();
#pragma unroll
  for (int c = 0; c < 16; ++c) {
    if (c < 11)
      asm volatile("global_load_dwordx4 %0, %1, off offset:%2 sc0 sc1"
                   : "=v"(sreg[c % 5]) : "v"(gp), "i"((c + 5) * 128));
    if (c < 15) {
      asm volatile("s_waitcnt vmcnt(%0)" :: "i"((c < 11) ? 4 : (14 - c)));
      __builtin_amdgcn_sched_barrier(0);
      *(v8s*)(wp + ((c + 1) & 1) * 8192) = sreg[(c + 1) % 5];
    }
    const char* buf = rp + (c & 1) * 8192;
#pragma unroll
    for (int ls = 0; ls < 2; ++ls) {
      v8s a = *(const v8s*)(buf + ((ls * 64 + lk2) ^ swz));
      v8s b = *(const v8s*)(bb + (((c * 2 + ls) * 64 + lk2) ^ swz));
      acc = __builtin_amdgcn_mfma_f32_16x16x32_bf16(a, b, acc, 0, 0, 0);
    }
    __syncthreads();
  }
  return acc;
}

// ---------------- persistent 2-layer GRU recurrence -------------------------------
// 192 WGs x 512 thr. LDS: [0,64K) P1 weights (32 cols); [64K,128K) P2 weights
// (32 cols, wg<96); [128K,144K) A-stage dbuf. State via sc0sc1 LLC atomics.
// Per tick (2 barriers):
//  P1: rz0(T) wg0-63 | xp1(T-1) wg64-159 | ht1(T-2) wg160-191   (32 cols, staged A)
//  P2: ht0(T) wg0-31 | rz1(T-1) wg32-95                          (32 cols, staged A)
__global__ void __launch_bounds__(TPB_REC, 2) k_recur(
    const u16* __restrict__ Uh0b, const u16* __restrict__ Wx1b, const u16* __restrict__ Uh1b,
    const float* __restrict__ b0, const float* __restrict__ b1,
    const u16* __restrict__ xa0,
    float* __restrict__ h0f, u16* __restrict__ h0b,
    float* __restrict__ h1f, u16* __restrict__ h1b,
    u16* __restrict__ a2, float* __restrict__ z0,
    u16* __restrict__ a5, float* __restrict__ z1,
    u16* __restrict__ xp1,
    u16* __restrict__ hs1,
    float* __restrict__ outh,
    int* __restrict__ bar) {
  extern __shared__ char smem[];
  const int wg = blockIdx.x;
  const int t = threadIdx.x;
  const int w = t >> 6;
  const int l = t & 63;
  const int lr = l & 15;
  const int lk2 = (l >> 4) * 16;
  const int rg = w >> 1, cg = w & 1;
  const int rbase = rg * 16 + ((l >> 4) << 2);
  const int swz = (lr & 7) << 4;
  char* stage = smem + 131072;

  unsigned* a2u  = (unsigned*)a2;
  unsigned* a5u  = (unsigned*)a5;
  unsigned* h0bu = (unsigned*)h0b;
  unsigned* h1bu = (unsigned*)h1b;
  unsigned* xpu  = (unsigned*)xp1;

  // ---- one-time weight staging into swizzled LDS ----
  {
    const u16* w1src; int w1row0;
    if (wg < 64)       { w1src = Uh0b; w1row0 = wg * 32; }
    else if (wg < 160) { w1src = Wx1b; w1row0 = (wg - 64) * 32; }
    else               { w1src = Uh1b; w1row0 = 2048 + (wg - 160) * 32; }
    for (int i = t; i < 4096; i += TPB_REC) {          // 32 cols * 128 x 16B
      int c = i >> 7, j = i & 127;
      v8s v = *(const v8s*)(w1src + (size_t)(w1row0 + c) * HDIM + j * 8);
      *(v8s*)(smem + c * 2048 + ((j * 16) ^ ((c & 7) << 4))) = v;
    }
    if (wg < 96) {
      const u16* w2src; int w2row0;
      if (wg < 32) { w2src = Uh0b; w2row0 = 2048 + wg * 32; }
      else         { w2src = Uh1b; w2row0 = (wg - 32) * 32; }
      for (int i = t; i < 4096; i += TPB_REC) {
        int c = i >> 7, j = i & 127;
        v8s v = *(const v8s*)(w2src + (size_t)(w2row0 + c) * HDIM + j * 8);
        *(v8s*)(smem + 65536 + c * 2048 + ((j * 16) ^ ((c & 7) << 4))) = v;
      }
    }
    __syncthreads();
  }

  const char* bb1 = smem + (cg * 16 + lr) * 2048;
  const char* bb2 = smem + 65536 + (cg * 16 + lr) * 2048;

  for (int T = 0; T <= SLEN + 1; ++T) {
    // ---------------- Phase 1 ----------------
    if (wg < 64) {
      if (T < SLEN) {          // rz0(T): A=h0b, B=Uh0[rz]
        const int cglob = wg * 32 + cg * 16 + lr;      // 0..2047
        const int g = cglob >> 10;                     // uniform per WG
        const int o = cglob & 1023;
        const float bias = b0[g * HDIM + o];
        float xv[4], hv[4];
#pragma unroll
        for (int r = 0; r < 4; ++r) {
          int b = rbase + r;
          xv[r] = bf2f(xa0[((T * 3 + g) * BAT + b) * HDIM + o]);
          if (g == 0) hv[r] = ld_f32(&h0f[b * HDIM + o]);
        }
        v4f acc = gemm_staged((const char*)h0b, stage, bb1, swz, t, rg, lr, lk2);
#pragma unroll
        for (int r = 0; r < 4; ++r) {
          int b = rbase + r;
          float s = sigm(acc[r] + xv[r] + bias);
          if (g == 0) st_bf16_pair(a2u, b * HDIM + o, f2bf(s * hv[r]), l);
          else        st_f32(&z0[b * HDIM + o], s);
        }
      }
    } else if (wg < 160) {
      if (T >= 1 && T <= SLEN) {   // xp1(T-1): A=h0b, B=Wx1
        const int n = (wg - 64) * 32 + cg * 16 + lr;   // 0..3071
        v4f acc = gemm_staged((const char*)h0b, stage, bb1, swz, t, rg, lr, lk2);
        unsigned* xp = xpu + ((((T - 1) & 1) * (BAT * 3 * HDIM)) >> 1);
#pragma unroll
        for (int r = 0; r < 4; ++r)
          st_bf16_pair(xp, (rbase + r) * 3072 + n, f2bf(acc[r]), l);
      }
    } else {
      if (T >= 2) {                // ht1(T-2): A=a5, B=Uh1[h]
        const int t5 = T - 2;
        const int o = (wg - 160) * 32 + cg * 16 + lr;  // 0..1023
        const unsigned* xp = xpu + (((t5 & 1) * (BAT * 3 * HDIM)) >> 1);
        const float bias = b1[2 * HDIM + o];
        float pv[4], zv[4], hv[4];
#pragma unroll
        for (int r = 0; r < 4; ++r) {
          int b = rbase + r;
          pv[r] = ld_bf16(xp, b * 3072 + 2048 + o);
          zv[r] = ld_f32(&z1[b * HDIM + o]);
          hv[r] = ld_f32(&h1f[b * HDIM + o]);
        }
        v4f acc = gemm_staged((const char*)a5, stage, bb1, swz, t, rg, lr, lk2);
#pragma unroll
        for (int r = 0; r < 4; ++r) {
          int b = rbase + r;
          float ht = tanh_f(pv[r] + acc[r] + bias);
          float hn = (1.f - zv[r]) * hv[r] + zv[r] * ht;
          u16 hb = f2bf(hn);
          st_f32(&h1f[b * HDIM + o], hn);
          st_bf16_pair(h1bu, b * HDIM + o, hb, l);
          hs1[((size_t)t5 * BAT + b) * HDIM + o] = hb;           // normal store
          if (t5 == SLEN - 1) outh[(size_t)BAT * HDIM + b * HDIM + o] = hn;
        }
      }
    }
    gbar(bar, 2 * T + 1, wg, t);
    // ---------------- Phase 2 ----------------
    if (wg < 32) {
      if (T < SLEN) {              // ht0(T): A=a2, B=Uh0[h]
        const int o = wg * 32 + cg * 16 + lr;          // 0..1023
        const float bias = b0[2 * HDIM + o];
        float xv[4], zv[4], hv[4];
#pragma unroll
        for (int r = 0; r < 4; ++r) {
          int b = rbase + r;
          xv[r] = bf2f(xa0[((T * 3 + 2) * BAT + b) * HDIM + o]);
          zv[r] = ld_f32(&z0[b * HDIM + o]);
          hv[r] = ld_f32(&h0f[b * HDIM + o]);
        }
        v4f acc = gemm_staged((const char*)a2, stage, bb2, swz, t, rg, lr, lk2);
#pragma unroll
        for (int r = 0; r < 4; ++r) {
          int b = rbase + r;
          float ht = tanh_f(xv[r] + acc[r] + bias);
          float hn = (1.f - zv[r]) * hv[r] + zv[r] * ht;
          st_f32(&h0f[b * HDIM + o], hn);
          st_bf16_pair(h0bu, b * HDIM + o, f2bf(hn), l);
          if (T == SLEN - 1) outh[b * HDIM + o] = hn;
        }
      }
    } else if (wg < 96) {
      if (T >= 1 && T <= SLEN) {   // rz1(T-1): A=h1b, B=Uh1[rz]
        const int t4 = T - 1;
        const int cglob = (wg - 32) * 32 + cg * 16 + lr;  // 0..2047
        const int g = cglob >> 10;                        // uniform per WG
        const int o = cglob & 1023;
        const unsigned* xp = xpu + (((t4 & 1) * (BAT * 3 * HDIM)) >> 1);
        const float bias = b1[g * HDIM + o];
        float pv[4], hv[4];
#pragma unroll
        for (int r = 0; r < 4; ++r) {
          int b = rbase + r;
          pv[r] = ld_bf16(xp, b * 3072 + g * HDIM + o);
          if (g == 0) hv[r] = ld_f32(&h1f[b * HDIM + o]);
        }
        v4f acc = gemm_staged((const char*)h1b, stage, bb2, swz, t, rg, lr, lk2);
#pragma unroll
        for (int r = 0; r < 4; ++r) {
          int b = rbase + r;
          float s = sigm(acc[r] + pv[r] + bias);
          if (g == 0) st_bf16_pair(a5u, b * HDIM + o, f2bf(s * hv[r]), l);
          else        st_f32(&z1[b * HDIM + o], s);
        }
      }
    }
    gbar(bar, 2 * T + 2, wg, t);
  }
}

// ---------------- m97-style 128x128 bf16 GEMM ------------------------------------
// MODE 0: xa0 = gather(emb)[8192,512] x Wx0[3072,512]^T -> bf16 out in (S,3,B,H) layout
// MODE 1: logits = hs1[8192,1024] x Wd[VPAD,1024]^T + bd -> f32 (8192,10000)
template <int MODE>
__global__ void __launch_bounds__(256) k_gemm(
    const u16* __restrict__ A, const u16* __restrict__ Bw,
    const int* __restrict__ gidx, const float* __restrict__ bias,
    void* __restrict__ Out) {
  constexpr int K = MODE ? 1024 : 512;
  constexpr int NB_N = MODE ? (VPAD / 128) : (3072 / 128);

  __shared__ u16 sA[128 * 64];
  __shared__ u16 sB[128 * 64];

  const int nwg = gridDim.x;
  const int cpx = nwg >> 3;
  const int bid = blockIdx.x;
  const int swz = (bid & 7) * cpx + (bid >> 3);
  const int bm = swz / NB_N, bn = swz % NB_N;
  const int m0 = bm * 128, n0 = bn * 128;

  const int t = threadIdx.x;
  const int w = t >> 6, l = t & 63;
  const int lr = l & 15, lk = (l >> 4) * 8;
  const int wm = (w >> 1) * 64, wn = (w & 1) * 64;
  const int kc = (t & 7) * 8;

  int arowg[4];
#pragma unroll
  for (int i = 0; i < 4; ++i) {
    int row = m0 + i * 32 + (t >> 3);
    arowg[i] = (MODE == 0) ? gidx[row] : row;
  }
  int brow[4];
#pragma unroll
  for (int i = 0; i < 4; ++i) brow[i] = n0 + i * 32 + (t >> 3);

  v4f acc[4][4];
#pragma unroll
  for (int mi = 0; mi < 4; ++mi)
#pragma unroll
    for (int ni = 0; ni < 4; ++ni) acc[mi][ni] = v4f{0.f, 0.f, 0.f, 0.f};

  for (int k0 = 0; k0 < K; k0 += 64) {
    __syncthreads();
#pragma unroll
    for (int i = 0; i < 4; ++i) {
      const u16* src = A + (size_t)arowg[i] * K + k0 + kc;
      __builtin_amdgcn_global_load_lds((const __attribute__((address_space(1))) void*)src,
                                       (__attribute__((address_space(3))) void*)(sA + i * 2048 + w * 512),
                                       16, 0, 0);
    }
#pragma unroll
    for (int i = 0; i < 4; ++i) {
      const u16* src = Bw + (size_t)brow[i] * K + k0 + kc;
      __builtin_amdgcn_global_load_lds((const __attribute__((address_space(1))) void*)src,
                                       (__attribute__((address_space(3))) void*)(sB + i * 2048 + w * 512),
                                       16, 0, 0);
    }
    asm volatile("s_waitcnt vmcnt(0)" ::: "memory");
    __syncthreads();
#pragma unroll
    for (int ks = 0; ks < 2; ++ks) {
      v8s af[4], bfr[4];
#pragma unroll
      for (int mi = 0; mi < 4; ++mi) af[mi] = *(const v8s*)&sA[(wm + mi * 16 + lr) * 64 + ks * 32 + lk];
#pragma unroll
      for (int ni = 0; ni < 4; ++ni) bfr[ni] = *(const v8s*)&sB[(wn + ni * 16 + lr) * 64 + ks * 32 + lk];
#pragma unroll
      for (int mi = 0; mi < 4; ++mi)
#pragma unroll
        for (int ni = 0; ni < 4; ++ni)
          acc[mi][ni] = __builtin_amdgcn_mfma_f32_16x16x32_bf16(af[mi], bfr[ni], acc[mi][ni], 0, 0, 0);
    }
  }

#pragma unroll
  for (int mi = 0; mi < 4; ++mi)
#pragma unroll
    for (int ni = 0; ni < 4; ++ni)
#pragma unroll
      for (int r = 0; r < 4; ++r) {
        int grow = m0 + wm + mi * 16 + ((l >> 4) << 2) + r;
        int gcol = n0 + wn + ni * 16 + lr;
        float v = acc[mi][ni][r];
        if (MODE == 0) {
          int s = grow >> 6, b = grow & 63;
          int g = gcol >> 10, o = gcol & 1023;
          ((u16*)Out)[(((size_t)s * 3 + g) * BAT + b) * HDIM + o] = f2bf(v);
        } else {
          if (gcol < VOC) ((float*)Out)[(size_t)grow * VOC + gcol] = v + bias[gcol];
        }
      }
}

// ---------------- small helper kernels --------------------------------------------
__global__ void k_cvt(const float* __restrict__ src, u16* __restrict__ dst, int n, int nsrc) {
  int i = (blockIdx.x * 256 + threadIdx.x) * 4;
  if (i >= n) return;
#pragma unroll
  for (int j = 0; j < 4; ++j) {
    int idx = i + j;
    if (idx < n) dst[idx] = (idx < nsrc) ? f2bf(src[idx]) : (u16)0;
  }
}

__global__ void k_init(const float* __restrict__ hidden,
                       float* h0f, u16* h0b, float* h1f, u16* h1b, int* bar) {
  int i = blockIdx.x * 256 + threadIdx.x;
  if (i < BAT * HDIM) {
    float v0 = hidden[i];
    float v1 = hidden[BAT * HDIM + i];
    h0f[i] = v0; h0b[i] = f2bf(v0);
    h1f[i] = v1; h1b[i] = f2bf(v1);
  }
  if (i < 512) bar[i] = 0;
}

// ---------------- launcher ---------------------------------------------------------
extern "C" void kernel_launch(void* const* d_in, const int* in_sizes, int n_in,
                              void* d_out, int out_size, void* d_ws, size_t ws_size,
                              hipStream_t stream) {
  const int*   inp = (const int*)d_in[0];
  const float* hid = (const float*)d_in[1];
  const float* emb = (const float*)d_in[2];
  const float* Wx0 = (const float*)d_in[3];
  const float* Uh0 = (const float*)d_in[4];
  const float* b0  = (const float*)d_in[5];
  const float* Wx1 = (const float*)d_in[6];
  const float* Uh1 = (const float*)d_in[7];
  const float* b1  = (const float*)d_in[8];
  const float* Wd  = (const float*)d_in[9];
  const float* bd  = (const float*)d_in[10];

  char* ws = (char*)d_ws;
  size_t off = 0;
  auto alloc = [&](size_t bytes) {
    void* p = ws + off;
    off = (off + bytes + 255) & ~(size_t)255;
    return p;
  };
  u16* emb_b = (u16*)alloc(sizeof(u16) * (size_t)VOC * EDIM);
  u16* Wx0_b = (u16*)alloc(sizeof(u16) * 3 * HDIM * EDIM);
  u16* Uh0_b = (u16*)alloc(sizeof(u16) * 3 * HDIM * HDIM);
  u16* Wx1_b = (u16*)alloc(sizeof(u16) * 3 * HDIM * HDIM);
  u16* Uh1_b = (u16*)alloc(sizeof(u16) * 3 * HDIM * HDIM);
  u16* Wd_b  = (u16*)alloc(sizeof(u16) * (size_t)VPAD * HDIM);
  u16* xa0_b = (u16*)alloc(sizeof(u16) * (size_t)SLEN * 3 * BAT * HDIM);
  u16* hs1_b = (u16*)alloc(sizeof(u16) * (size_t)SLEN * BAT * HDIM);
  u16* xp1   = (u16*)alloc(sizeof(u16) * 2 * BAT * 3 * HDIM);
  float* h0f = (float*)alloc(sizeof(float) * BAT * HDIM);
  float* h1f = (float*)alloc(sizeof(float) * BAT * HDIM);
  u16* h0b   = (u16*)alloc(sizeof(u16) * BAT * HDIM);
  u16* h1b   = (u16*)alloc(sizeof(u16) * BAT * HDIM);
  u16* a2    = (u16*)alloc(sizeof(u16) * BAT * HDIM);
  u16* a5    = (u16*)alloc(sizeof(u16) * BAT * HDIM);
  float* z0  = (float*)alloc(sizeof(float) * BAT * HDIM);
  float* z1  = (float*)alloc(sizeof(float) * BAT * HDIM);
  int* bar   = (int*)alloc(sizeof(int) * 512);

  float* logits = (float*)d_out;
  float* outh = logits + (size_t)SLEN * BAT * VOC;

  auto cvt = [&](const float* s, u16* d, int n, int nsrc) {
    k_cvt<<<dim3((n / 4 + 255) / 256), dim3(256), 0, stream>>>(s, d, n, nsrc);
  };
  cvt(emb, emb_b, VOC * EDIM, VOC * EDIM);
  cvt(Wx0, Wx0_b, 3 * HDIM * EDIM, 3 * HDIM * EDIM);
  cvt(Uh0, Uh0_b, 3 * HDIM * HDIM, 3 * HDIM * HDIM);
  cvt(Wx1, Wx1_b, 3 * HDIM * HDIM, 3 * HDIM * HDIM);
  cvt(Uh1, Uh1_b, 3 * HDIM * HDIM, 3 * HDIM * HDIM);
  cvt(Wd, Wd_b, VPAD * HDIM, VOC * HDIM);
  k_init<<<dim3(256), dim3(256), 0, stream>>>(hid, h0f, h0b, h1f, h1b, bar);

  k_gemm<0><<<dim3(64 * 24), dim3(256), 0, stream>>>(emb_b, Wx0_b, inp, (const float*)nullptr, (void*)xa0_b);

  (void)hipFuncSetAttribute(reinterpret_cast<const void*>(k_recur),
                            hipFuncAttributeMaxDynamicSharedMemorySize, 147456);
  k_recur<<<dim3(NWG_REC), dim3(TPB_REC), 147456, stream>>>(
      Uh0_b, Wx1_b, Uh1_b, b0, b1, xa0_b,
      h0f, h0b, h1f, h1b, a2, z0, a5, z1, xp1, hs1_b, outh, bar);

  k_gemm<1><<<dim3(64 * 79), dim3(256), 0, stream>>>(hs1_b, Wd_b, (const int*)nullptr, bd, d_out);
}

// Round 13
// 2476.402 us; speedup vs baseline: 2.2754x; 1.1727x over previous
//
#include <hip/hip_runtime.h>
#include <hip/hip_bf16.h>

#define SLEN 128
#define BAT 64
#define EDIM 512
#define HDIM 1024
#define VOC 10000
#define VPAD 10112     // 79 * 128
#define NWG_REC 192
#define TPB_REC 512

typedef short v8s __attribute__((ext_vector_type(8)));
typedef float v4f __attribute__((ext_vector_type(4)));
typedef unsigned short u16;

__device__ __forceinline__ u16 f2bf(float f) {
  unsigned u = __float_as_uint(f);
  u += 0x7fffu + ((u >> 16) & 1u);   // RNE
  return (u16)(u >> 16);
}
__device__ __forceinline__ float bf2f(u16 b) {
  return __uint_as_float(((unsigned)b) << 16);
}
__device__ __forceinline__ float sigm(float x) { return 1.f / (1.f + __expf(-x)); }
__device__ __forceinline__ float tanh_f(float x) { return 1.f - 2.f / (1.f + __expf(2.f * x)); }

// ---- LLC-point scalar state accessors (relaxed agent atomics, no fences) ---------
__device__ __forceinline__ void st_f32(float* p, float v) {
  __hip_atomic_store(p, v, __ATOMIC_RELAXED, __HIP_MEMORY_SCOPE_AGENT);
}
__device__ __forceinline__ float ld_f32(const float* p) {
  return __hip_atomic_load(p, __ATOMIC_RELAXED, __HIP_MEMORY_SCOPE_AGENT);
}
__device__ __forceinline__ float ld_bf16(const unsigned* base, int elem) {
  unsigned pr = __hip_atomic_load(base + (elem >> 1), __ATOMIC_RELAXED, __HIP_MEMORY_SCOPE_AGENT);
  return bf2f((u16)((elem & 1) ? (pr >> 16) : (pr & 0xffffu)));
}
// bf16 pair store: lanes l (even) and l^1 hold adjacent elements; even lane stores u32
__device__ __forceinline__ void st_bf16_pair(unsigned* base, int elem, u16 val, int l) {
  unsigned p = (unsigned)__shfl_xor((int)val, 1);
  if ((l & 1) == 0)
    __hip_atomic_store(base + (elem >> 1), (unsigned)val | (p << 16),
                       __ATOMIC_RELAXED, __HIP_MEMORY_SCOPE_AGENT);
}

// ---------------- full-poll barrier (used once for leader election) ----------------
__device__ __forceinline__ void gbar_full(int* bar, int ph, int wg, int t) {
  asm volatile("s_waitcnt vmcnt(0) lgkmcnt(0)" ::: "memory");
  __syncthreads();
  if (t == 0)
    __hip_atomic_store(&bar[wg], ph, __ATOMIC_RELAXED, __HIP_MEMORY_SCOPE_AGENT);
  if (t < 64) {
    for (;;) {
      int v0 = __hip_atomic_load(&bar[t],       __ATOMIC_RELAXED, __HIP_MEMORY_SCOPE_AGENT);
      int v1 = __hip_atomic_load(&bar[64 + t],  __ATOMIC_RELAXED, __HIP_MEMORY_SCOPE_AGENT);
      int v2 = __hip_atomic_load(&bar[128 + t], __ATOMIC_RELAXED, __HIP_MEMORY_SCOPE_AGENT);
      if (__all((v0 >= ph) & (v1 >= ph) & (v2 >= ph))) break;
      __builtin_amdgcn_s_sleep(1);
    }
  }
  __syncthreads();
}

// ---------------- leader-inv barrier ----------------------------------------------
// Producers drain + post flags (sc). Per XCD, ONE leader WG polls all 192 flags,
// issues ONE buffer_inv sc1 (L2 invalidate) and posts inv_flag[xcd]; the other WGs
// poll only their XCD's inv_flag. Then each WG does one L1 buffer_inv and proceeds
// with NORMAL (L2-cached) loads: first toucher fills L2 from LLC, rest hit L2.
// All k_recur stores are sc (LLC-point) -> inv never drops dirty data.
__device__ __forceinline__ void gbar_inv(int* bar, int ph, int wg, int t,
                                         int xcc, bool lead) {
  asm volatile("s_waitcnt vmcnt(0) lgkmcnt(0)" ::: "memory");
  __syncthreads();
  if (t == 0)
    __hip_atomic_store(&bar[wg], ph, __ATOMIC_RELAXED, __HIP_MEMORY_SCOPE_AGENT);
  if (lead) {
    if (t < 64) {
      for (;;) {
        int v0 = __hip_atomic_load(&bar[t],       __ATOMIC_RELAXED, __HIP_MEMORY_SCOPE_AGENT);
        int v1 = __hip_atomic_load(&bar[64 + t],  __ATOMIC_RELAXED, __HIP_MEMORY_SCOPE_AGENT);
        int v2 = __hip_atomic_load(&bar[128 + t], __ATOMIC_RELAXED, __HIP_MEMORY_SCOPE_AGENT);
        if (__all((v0 >= ph) & (v1 >= ph) & (v2 >= ph))) break;
        __builtin_amdgcn_s_sleep(1);
      }
      if (t == 0) {
        asm volatile("buffer_inv sc1" ::: "memory");           // XCD L2 invalidate
        asm volatile("s_waitcnt vmcnt(0)" ::: "memory");
        __hip_atomic_store(&bar[256 + xcc], ph, __ATOMIC_RELAXED, __HIP_MEMORY_SCOPE_AGENT);
      }
    }
  } else {
    if (t < 64) {
      while (__hip_atomic_load(&bar[256 + xcc], __ATOMIC_RELAXED, __HIP_MEMORY_SCOPE_AGENT) < ph)
        __builtin_amdgcn_s_sleep(1);
    }
  }
  if (t < 64) {
    asm volatile("buffer_inv" ::: "memory");                   // CU L1 invalidate
    asm volatile("s_waitcnt vmcnt(0)" ::: "memory");
  }
  __syncthreads();
}

// ---- cooperative LDS-staged 64x(32cols)x1024 GEMM (depth-3 ring, L2-cached A) ----
__device__ __forceinline__ v4f gemm_staged(const char* Asrc, char* stage,
                                           const char* bb, int swz,
                                           int t, int rg, int lr, int lk2) {
  const char* gp = Asrc + (t >> 3) * 2048 + (t & 7) * 16;
  char* wp = stage + (t >> 3) * 128 + (((t & 7) * 16) ^ (((t >> 3) & 7) << 4));
  const char* rp = stage + (rg * 16 + lr) * 128;
  v4f acc{0.f, 0.f, 0.f, 0.f};
  v8s sreg[3];
  asm volatile("global_load_dwordx4 %0, %1, off" : "=v"(sreg[0]) : "v"(gp));
  asm volatile("global_load_dwordx4 %0, %1, off offset:128" : "=v"(sreg[1]) : "v"(gp));
  asm volatile("global_load_dwordx4 %0, %1, off offset:256" : "=v"(sreg[2]) : "v"(gp));
  asm volatile("s_waitcnt vmcnt(2)" ::: "memory");
  __builtin_amdgcn_sched_barrier(0);
  *(v8s*)wp = sreg[0];
  __syncthreads();
#pragma unroll
  for (int c = 0; c < 16; ++c) {
    if (c < 13)
      asm volatile("global_load_dwordx4 %0, %1, off offset:%2"
                   : "=v"(sreg[c % 3]) : "v"(gp), "i"((c + 3) * 128));
    if (c < 15) {
      if (c < 13)       asm volatile("s_waitcnt vmcnt(2)" ::: "memory");
      else if (c == 13) asm volatile("s_waitcnt vmcnt(1)" ::: "memory");
      else              asm volatile("s_waitcnt vmcnt(0)" ::: "memory");
      __builtin_amdgcn_sched_barrier(0);
      *(v8s*)(wp + ((c + 1) & 1) * 8192) = sreg[(c + 1) % 3];
    }
    const char* buf = rp + (c & 1) * 8192;
#pragma unroll
    for (int ls = 0; ls < 2; ++ls) {
      v8s a = *(const v8s*)(buf + ((ls * 64 + lk2) ^ swz));
      v8s b = *(const v8s*)(bb + (((c * 2 + ls) * 64 + lk2) ^ swz));
      acc = __builtin_amdgcn_mfma_f32_16x16x32_bf16(a, b, acc, 0, 0, 0);
    }
    __syncthreads();
  }
  return acc;
}

// ---------------- persistent 2-layer GRU recurrence -------------------------------
// 192 WGs x 512 thr. LDS: [0,64K) P1 weights (32 cols); [64K,128K) P2 weights
// (32 cols, wg<96); [128K,144K) A-stage dbuf. State stores via sc LLC atomics;
// A-operand via L2-cached loads + leader-inv barrier.
// Per tick (2 barriers):
//  P1: rz0(T) wg0-63 | xp1(T-1) wg64-159 | ht1(T-2) wg160-191   (32 cols, staged A)
//  P2: ht0(T) wg0-31 | rz1(T-1) wg32-95                          (32 cols, staged A)
__global__ void __launch_bounds__(TPB_REC, 2) k_recur(
    const u16* __restrict__ Uh0b, const u16* __restrict__ Wx1b, const u16* __restrict__ Uh1b,
    const float* __restrict__ b0, const float* __restrict__ b1,
    const u16* __restrict__ xa0,
    float* __restrict__ h0f, u16* __restrict__ h0b,
    float* __restrict__ h1f, u16* __restrict__ h1b,
    u16* __restrict__ a2, float* __restrict__ z0,
    u16* __restrict__ a5, float* __restrict__ z1,
    u16* __restrict__ xp1,
    u16* __restrict__ hs1,
    float* __restrict__ outh,
    int* __restrict__ bar) {
  extern __shared__ char smem[];
  const int wg = blockIdx.x;
  const int t = threadIdx.x;
  const int w = t >> 6;
  const int l = t & 63;
  const int lr = l & 15;
  const int lk2 = (l >> 4) * 16;
  const int rg = w >> 1, cg = w & 1;
  const int rbase = rg * 16 + ((l >> 4) << 2);
  const int swz = (lr & 7) << 4;
  char* stage = smem + 131072;

  unsigned* a2u  = (unsigned*)a2;
  unsigned* a5u  = (unsigned*)a5;
  unsigned* h0bu = (unsigned*)h0b;
  unsigned* h1bu = (unsigned*)h1b;
  unsigned* xpu  = (unsigned*)xp1;
  unsigned* hs1u = (unsigned*)hs1;

  // ---- one-time weight staging into swizzled LDS ----
  {
    const u16* w1src; int w1row0;
    if (wg < 64)       { w1src = Uh0b; w1row0 = wg * 32; }
    else if (wg < 160) { w1src = Wx1b; w1row0 = (wg - 64) * 32; }
    else               { w1src = Uh1b; w1row0 = 2048 + (wg - 160) * 32; }
    for (int i = t; i < 4096; i += TPB_REC) {          // 32 cols * 128 x 16B
      int c = i >> 7, j = i & 127;
      v8s v = *(const v8s*)(w1src + (size_t)(w1row0 + c) * HDIM + j * 8);
      *(v8s*)(smem + c * 2048 + ((j * 16) ^ ((c & 7) << 4))) = v;
    }
    if (wg < 96) {
      const u16* w2src; int w2row0;
      if (wg < 32) { w2src = Uh0b; w2row0 = 2048 + wg * 32; }
      else         { w2src = Uh1b; w2row0 = (wg - 32) * 32; }
      for (int i = t; i < 4096; i += TPB_REC) {
        int c = i >> 7, j = i & 127;
        v8s v = *(const v8s*)(w2src + (size_t)(w2row0 + c) * HDIM + j * 8);
        *(v8s*)(smem + 65536 + c * 2048 + ((j * 16) ^ ((c & 7) << 4))) = v;
      }
    }
    __syncthreads();
  }

  // ---- leader election: min wg-id per XCD ----
  int xcc;
  asm volatile("s_getreg_b32 %0, hwreg(HW_REG_XCC_ID)" : "=s"(xcc));
  xcc &= 7;
  if (t == 0)
    (void)__hip_atomic_fetch_min(&bar[320 + xcc], wg, __ATOMIC_RELAXED, __HIP_MEMORY_SCOPE_AGENT);
  gbar_full(bar, 1, wg, t);
  const bool lead =
      (__hip_atomic_load(&bar[320 + xcc], __ATOMIC_RELAXED, __HIP_MEMORY_SCOPE_AGENT) == wg);

  const char* bb1 = smem + (cg * 16 + lr) * 2048;
  const char* bb2 = smem + 65536 + (cg * 16 + lr) * 2048;

  for (int T = 0; T <= SLEN + 1; ++T) {
    // ---------------- Phase 1 ----------------
    if (wg < 64) {
      if (T < SLEN) {          // rz0(T): A=h0b, B=Uh0[rz]
        const int cglob = wg * 32 + cg * 16 + lr;      // 0..2047
        const int g = cglob >> 10;                     // uniform per WG
        const int o = cglob & 1023;
        const float bias = b0[g * HDIM + o];
        float xv[4], hv[4];
#pragma unroll
        for (int r = 0; r < 4; ++r) {
          int b = rbase + r;
          xv[r] = bf2f(xa0[((T * 3 + g) * BAT + b) * HDIM + o]);
          if (g == 0) hv[r] = ld_f32(&h0f[b * HDIM + o]);
        }
        v4f acc = gemm_staged((const char*)h0b, stage, bb1, swz, t, rg, lr, lk2);
#pragma unroll
        for (int r = 0; r < 4; ++r) {
          int b = rbase + r;
          float s = sigm(acc[r] + xv[r] + bias);
          if (g == 0) st_bf16_pair(a2u, b * HDIM + o, f2bf(s * hv[r]), l);
          else        st_f32(&z0[b * HDIM + o], s);
        }
      }
    } else if (wg < 160) {
      if (T >= 1 && T <= SLEN) {   // xp1(T-1): A=h0b, B=Wx1
        const int n = (wg - 64) * 32 + cg * 16 + lr;   // 0..3071
        v4f acc = gemm_staged((const char*)h0b, stage, bb1, swz, t, rg, lr, lk2);
        unsigned* xp = xpu + ((((T - 1) & 1) * (BAT * 3 * HDIM)) >> 1);
#pragma unroll
        for (int r = 0; r < 4; ++r)
          st_bf16_pair(xp, (rbase + r) * 3072 + n, f2bf(acc[r]), l);
      }
    } else {
      if (T >= 2) {                // ht1(T-2): A=a5, B=Uh1[h]
        const int t5 = T - 2;
        const int o = (wg - 160) * 32 + cg * 16 + lr;  // 0..1023
        const unsigned* xp = xpu + (((t5 & 1) * (BAT * 3 * HDIM)) >> 1);
        const float bias = b1[2 * HDIM + o];
        float pv[4], zv[4], hv[4];
#pragma unroll
        for (int r = 0; r < 4; ++r) {
          int b = rbase + r;
          pv[r] = ld_bf16(xp, b * 3072 + 2048 + o);
          zv[r] = ld_f32(&z1[b * HDIM + o]);
          hv[r] = ld_f32(&h1f[b * HDIM + o]);
        }
        v4f acc = gemm_staged((const char*)a5, stage, bb1, swz, t, rg, lr, lk2);
#pragma unroll
        for (int r = 0; r < 4; ++r) {
          int b = rbase + r;
          float ht = tanh_f(pv[r] + acc[r] + bias);
          float hn = (1.f - zv[r]) * hv[r] + zv[r] * ht;
          u16 hb = f2bf(hn);
          st_f32(&h1f[b * HDIM + o], hn);
          st_bf16_pair(h1bu, b * HDIM + o, hb, l);
          st_bf16_pair(hs1u, (int)(((size_t)t5 * BAT + b) * HDIM + o), hb, l);
          if (t5 == SLEN - 1) st_f32(&outh[(size_t)BAT * HDIM + b * HDIM + o], hn);
        }
      }
    }
    gbar_inv(bar, 2 * T + 2, wg, t, xcc, lead);
    // ---------------- Phase 2 ----------------
    if (wg < 32) {
      if (T < SLEN) {              // ht0(T): A=a2, B=Uh0[h]
        const int o = wg * 32 + cg * 16 + lr;          // 0..1023
        const float bias = b0[2 * HDIM + o];
        float xv[4], zv[4], hv[4];
#pragma unroll
        for (int r = 0; r < 4; ++r) {
          int b = rbase + r;
          xv[r] = bf2f(xa0[((T * 3 + 2) * BAT + b) * HDIM + o]);
          zv[r] = ld_f32(&z0[b * HDIM + o]);
          hv[r] = ld_f32(&h0f[b * HDIM + o]);
        }
        v4f acc = gemm_staged((const char*)a2, stage, bb2, swz, t, rg, lr, lk2);
#pragma unroll
        for (int r = 0; r < 4; ++r) {
          int b = rbase + r;
          float ht = tanh_f(xv[r] + acc[r] + bias);
          float hn = (1.f - zv[r]) * hv[r] + zv[r] * ht;
          st_f32(&h0f[b * HDIM + o], hn);
          st_bf16_pair(h0bu, b * HDIM + o, f2bf(hn), l);
          if (T == SLEN - 1) st_f32(&outh[b * HDIM + o], hn);
        }
      }
    } else if (wg < 96) {
      if (T >= 1 && T <= SLEN) {   // rz1(T-1): A=h1b, B=Uh1[rz]
        const int t4 = T - 1;
        const int cglob = (wg - 32) * 32 + cg * 16 + lr;  // 0..2047
        const int g = cglob >> 10;                        // uniform per WG
        const int o = cglob & 1023;
        const unsigned* xp = xpu + (((t4 & 1) * (BAT * 3 * HDIM)) >> 1);
        const float bias = b1[g * HDIM + o];
        float pv[4], hv[4];
#pragma unroll
        for (int r = 0; r < 4; ++r) {
          int b = rbase + r;
          pv[r] = ld_bf16(xp, b * 3072 + g * HDIM + o);
          if (g == 0) hv[r] = ld_f32(&h1f[b * HDIM + o]);
        }
        v4f acc = gemm_staged((const char*)h1b, stage, bb2, swz, t, rg, lr, lk2);
#pragma unroll
        for (int r = 0; r < 4; ++r) {
          int b = rbase + r;
          float s = sigm(acc[r] + pv[r] + bias);
          if (g == 0) st_bf16_pair(a5u, b * HDIM + o, f2bf(s * hv[r]), l);
          else        st_f32(&z1[b * HDIM + o], s);
        }
      }
    }
    gbar_inv(bar, 2 * T + 3, wg, t, xcc, lead);
  }
}

// ---------------- m97-style 128x128 bf16 GEMM ------------------------------------
// MODE 0: xa0 = gather(emb)[8192,512] x Wx0[3072,512]^T -> bf16 out in (S,3,B,H) layout
// MODE 1: logits = hs1[8192,1024] x Wd[VPAD,1024]^T + bd -> f32 (8192,10000)
template <int MODE>
__global__ void __launch_bounds__(256) k_gemm(
    const u16* __restrict__ A, const u16* __restrict__ Bw,
    const int* __restrict__ gidx, const float* __restrict__ bias,
    void* __restrict__ Out) {
  constexpr int K = MODE ? 1024 : 512;
  constexpr int NB_N = MODE ? (VPAD / 128) : (3072 / 128);

  __shared__ u16 sA[128 * 64];
  __shared__ u16 sB[128 * 64];

  const int nwg = gridDim.x;
  const int cpx = nwg >> 3;
  const int bid = blockIdx.x;
  const int swz = (bid & 7) * cpx + (bid >> 3);
  const int bm = swz / NB_N, bn = swz % NB_N;
  const int m0 = bm * 128, n0 = bn * 128;

  const int t = threadIdx.x;
  const int w = t >> 6, l = t & 63;
  const int lr = l & 15, lk = (l >> 4) * 8;
  const int wm = (w >> 1) * 64, wn = (w & 1) * 64;
  const int kc = (t & 7) * 8;

  int arowg[4];
#pragma unroll
  for (int i = 0; i < 4; ++i) {
    int row = m0 + i * 32 + (t >> 3);
    arowg[i] = (MODE == 0) ? gidx[row] : row;
  }
  int brow[4];
#pragma unroll
  for (int i = 0; i < 4; ++i) brow[i] = n0 + i * 32 + (t >> 3);

  v4f acc[4][4];
#pragma unroll
  for (int mi = 0; mi < 4; ++mi)
#pragma unroll
    for (int ni = 0; ni < 4; ++ni) acc[mi][ni] = v4f{0.f, 0.f, 0.f, 0.f};

  for (int k0 = 0; k0 < K; k0 += 64) {
    __syncthreads();
#pragma unroll
    for (int i = 0; i < 4; ++i) {
      const u16* src = A + (size_t)arowg[i] * K + k0 + kc;
      __builtin_amdgcn_global_load_lds((const __attribute__((address_space(1))) void*)src,
                                       (__attribute__((address_space(3))) void*)(sA + i * 2048 + w * 512),
                                       16, 0, 0);
    }
#pragma unroll
    for (int i = 0; i < 4; ++i) {
      const u16* src = Bw + (size_t)brow[i] * K + k0 + kc;
      __builtin_amdgcn_global_load_lds((const __attribute__((address_space(1))) void*)src,
                                       (__attribute__((address_space(3))) void*)(sB + i * 2048 + w * 512),
                                       16, 0, 0);
    }
    asm volatile("s_waitcnt vmcnt(0)" ::: "memory");
    __syncthreads();
#pragma unroll
    for (int ks = 0; ks < 2; ++ks) {
      v8s af[4], bfr[4];
#pragma unroll
      for (int mi = 0; mi < 4; ++mi) af[mi] = *(const v8s*)&sA[(wm + mi * 16 + lr) * 64 + ks * 32 + lk];
#pragma unroll
      for (int ni = 0; ni < 4; ++ni) bfr[ni] = *(const v8s*)&sB[(wn + ni * 16 + lr) * 64 + ks * 32 + lk];
#pragma unroll
      for (int mi = 0; mi < 4; ++mi)
#pragma unroll
        for (int ni = 0; ni < 4; ++ni)
          acc[mi][ni] = __builtin_amdgcn_mfma_f32_16x16x32_bf16(af[mi], bfr[ni], acc[mi][ni], 0, 0, 0);
    }
  }

#pragma unroll
  for (int mi = 0; mi < 4; ++mi)
#pragma unroll
    for (int ni = 0; ni < 4; ++ni)
#pragma unroll
      for (int r = 0; r < 4; ++r) {
        int grow = m0 + wm + mi * 16 + ((l >> 4) << 2) + r;
        int gcol = n0 + wn + ni * 16 + lr;
        float v = acc[mi][ni][r];
        if (MODE == 0) {
          int s = grow >> 6, b = grow & 63;
          int g = gcol >> 10, o = gcol & 1023;
          ((u16*)Out)[(((size_t)s * 3 + g) * BAT + b) * HDIM + o] = f2bf(v);
        } else {
          if (gcol < VOC) ((float*)Out)[(size_t)grow * VOC + gcol] = v + bias[gcol];
        }
      }
}

// ---------------- small helper kernels --------------------------------------------
__global__ void k_cvt(const float* __restrict__ src, u16* __restrict__ dst, int n, int nsrc) {
  int i = (blockIdx.x * 256 + threadIdx.x) * 4;
  if (i >= n) return;
#pragma unroll
  for (int j = 0; j < 4; ++j) {
    int idx = i + j;
    if (idx < n) dst[idx] = (idx < nsrc) ? f2bf(src[idx]) : (u16)0;
  }
}

__global__ void k_init(const float* __restrict__ hidden,
                       float* h0f, u16* h0b, float* h1f, u16* h1b, int* bar) {
  int i = blockIdx.x * 256 + threadIdx.x;
  if (i < BAT * HDIM) {
    float v0 = hidden[i];
    float v1 = hidden[BAT * HDIM + i];
    h0f[i] = v0; h0b[i] = f2bf(v0);
    h1f[i] = v1; h1b[i] = f2bf(v1);
  }
  if (i < 512) bar[i] = (i >= 320 && i < 328) ? 0x7fffffff : 0;
}

// ---------------- launcher ---------------------------------------------------------
extern "C" void kernel_launch(void* const* d_in, const int* in_sizes, int n_in,
                              void* d_out, int out_size, void* d_ws, size_t ws_size,
                              hipStream_t stream) {
  const int*   inp = (const int*)d_in[0];
  const float* hid = (const float*)d_in[1];
  const float* emb = (const float*)d_in[2];
  const float* Wx0 = (const float*)d_in[3];
  const float* Uh0 = (const float*)d_in[4];
  const float* b0  = (const float*)d_in[5];
  const float* Wx1 = (const float*)d_in[6];
  const float* Uh1 = (const float*)d_in[7];
  const float* b1  = (const float*)d_in[8];
  const float* Wd  = (const float*)d_in[9];
  const float* bd  = (const float*)d_in[10];

  char* ws = (char*)d_ws;
  size_t off = 0;
  auto alloc = [&](size_t bytes) {
    void* p = ws + off;
    off = (off + bytes + 255) & ~(size_t)255;
    return p;
  };
  u16* emb_b = (u16*)alloc(sizeof(u16) * (size_t)VOC * EDIM);
  u16* Wx0_b = (u16*)alloc(sizeof(u16) * 3 * HDIM * EDIM);
  u16* Uh0_b = (u16*)alloc(sizeof(u16) * 3 * HDIM * HDIM);
  u16* Wx1_b = (u16*)alloc(sizeof(u16) * 3 * HDIM * HDIM);
  u16* Uh1_b = (u16*)alloc(sizeof(u16) * 3 * HDIM * HDIM);
  u16* Wd_b  = (u16*)alloc(sizeof(u16) * (size_t)VPAD * HDIM);
  u16* xa0_b = (u16*)alloc(sizeof(u16) * (size_t)SLEN * 3 * BAT * HDIM);
  u16* hs1_b = (u16*)alloc(sizeof(u16) * (size_t)SLEN * BAT * HDIM);
  u16* xp1   = (u16*)alloc(sizeof(u16) * 2 * BAT * 3 * HDIM);
  float* h0f = (float*)alloc(sizeof(float) * BAT * HDIM);
  float* h1f = (float*)alloc(sizeof(float) * BAT * HDIM);
  u16* h0b   = (u16*)alloc(sizeof(u16) * BAT * HDIM);
  u16* h1b   = (u16*)alloc(sizeof(u16) * BAT * HDIM);
  u16* a2    = (u16*)alloc(sizeof(u16) * BAT * HDIM);
  u16* a5    = (u16*)alloc(sizeof(u16) * BAT * HDIM);
  float* z0  = (float*)alloc(sizeof(float) * BAT * HDIM);
  float* z1  = (float*)alloc(sizeof(float) * BAT * HDIM);
  int* bar   = (int*)alloc(sizeof(int) * 512);

  float* logits = (float*)d_out;
  float* outh = logits + (size_t)SLEN * BAT * VOC;

  auto cvt = [&](const float* s, u16* d, int n, int nsrc) {
    k_cvt<<<dim3((n / 4 + 255) / 256), dim3(256), 0, stream>>>(s, d, n, nsrc);
  };
  cvt(emb, emb_b, VOC * EDIM, VOC * EDIM);
  cvt(Wx0, Wx0_b, 3 * HDIM * EDIM, 3 * HDIM * EDIM);
  cvt(Uh0, Uh0_b, 3 * HDIM * HDIM, 3 * HDIM * HDIM);
  cvt(Wx1, Wx1_b, 3 * HDIM * HDIM, 3 * HDIM * HDIM);
  cvt(Uh1, Uh1_b, 3 * HDIM * HDIM, 3 * HDIM * HDIM);
  cvt(Wd, Wd_b, VPAD * HDIM, VOC * HDIM);
  k_init<<<dim3(256), dim3(256), 0, stream>>>(hid, h0f, h0b, h1f, h1b, bar);

  k_gemm<0><<<dim3(64 * 24), dim3(256), 0, stream>>>(emb_b, Wx0_b, inp, (const float*)nullptr, (void*)xa0_b);

  (void)hipFuncSetAttribute(reinterpret_cast<const void*>(k_recur),
                            hipFuncAttributeMaxDynamicSharedMemorySize, 147456);
  k_recur<<<dim3(NWG_REC), dim3(TPB_REC), 147456, stream>>>(
      Uh0_b, Wx1_b, Uh1_b, b0, b1, xa0_b,
      h0f, h0b, h1f, h1b, a2, z0, a5, z1, xp1, hs1_b, outh, bar);

  k_gemm<1><<<dim3(64 * 79), dim3(256), 0, stream>>>(hs1_b, Wd_b, (const int*)nullptr, bd, d_out);
}